// Round 1
// baseline (200.431 us; speedup 1.0000x reference)
//
#include <hip/hip_runtime.h>
#include <math.h>

#define NPOS 4096
#define DCH  512
#define HD   32
#define NH   16
#define KW   9
#define DIL  3
#define PAD  12

__global__ __launch_bounds__(256) void dilate_attn_kernel(
    const float* __restrict__ q,
    const float* __restrict__ k,
    const float* __restrict__ v,
    float* __restrict__ out)
{
    const int t  = blockIdx.x * blockDim.x + threadIdx.x;
    const int n  = t & (NPOS - 1);
    const int bh = t >> 12;               // b*16 + h; channel base = bh*32

    const size_t chbase = (size_t)bh * HD * NPOS;
    const float* qp = q + chbase + n;
    const float* kp = k + chbase;
    const float* vp = v + chbase;

    // Window indices + validity (independent of channel)
    int   idx[KW];
    float validf[KW];
#pragma unroll
    for (int j = 0; j < KW; ++j) {
        int i0 = n + j * DIL - PAD;
        validf[j] = (i0 >= 0 && i0 < NPOS) ? 1.0f : 0.0f;
        idx[j] = min(max(i0, 0), NPOS - 1);
    }

    // Scores: s[j] = sum_c q[c] * k[c][idx[j]]
    float s[KW];
#pragma unroll
    for (int j = 0; j < KW; ++j) s[j] = 0.0f;

#pragma unroll 4
    for (int c = 0; c < HD; ++c) {
        float qc = qp[(size_t)c * NPOS];
        const float* kc = kp + (size_t)c * NPOS;
#pragma unroll
        for (int j = 0; j < KW; ++j)
            s[j] = fmaf(qc, kc[idx[j]], s[j]);
    }

    // Softmax over 9 slots; invalid slots have logit exactly 0
    const float scale = 0.17677669529663687f;  // 32^-0.5
    float m = -INFINITY;
#pragma unroll
    for (int j = 0; j < KW; ++j) {
        s[j] = s[j] * scale * validf[j];
        m = fmaxf(m, s[j]);
    }
    float sum = 0.0f;
    float p[KW];
#pragma unroll
    for (int j = 0; j < KW; ++j) {
        float e = __expf(s[j] - m);
        p[j] = e;
        sum += e;
    }
    float inv = 1.0f / sum;
#pragma unroll
    for (int j = 0; j < KW; ++j)
        p[j] *= inv * validf[j];   // invalid taps contribute nothing to output

    // Output: o[c] = sum_j p[j] * v[c][idx[j]]
    float o[HD];
#pragma unroll 4
    for (int c = 0; c < HD; ++c) {
        const float* vc = vp + (size_t)c * NPOS;
        float acc = 0.0f;
#pragma unroll
        for (int j = 0; j < KW; ++j)
            acc = fmaf(p[j], vc[idx[j]], acc);
        o[c] = acc;
    }

    // Store: out[(b*NPOS + n)*DCH + h*HD + c], 32 contiguous floats -> 8 float4
    const int b  = bh >> 4;
    const int hh = bh & (NH - 1);
    float* op = out + ((size_t)(b * NPOS + n)) * DCH + hh * HD;
    float4* op4 = reinterpret_cast<float4*>(op);
#pragma unroll
    for (int i = 0; i < HD / 4; ++i) {
        op4[i] = make_float4(o[4*i], o[4*i+1], o[4*i+2], o[4*i+3]);
    }
}

extern "C" void kernel_launch(void* const* d_in, const int* in_sizes, int n_in,
                              void* d_out, int out_size, void* d_ws, size_t ws_size,
                              hipStream_t stream) {
    const float* q = (const float*)d_in[0];
    const float* k = (const float*)d_in[1];
    const float* v = (const float*)d_in[2];
    float* out = (float*)d_out;

    const int total  = 4 * NH * NPOS;      // B * heads * L threads
    const int block  = 256;
    const int grid   = total / block;      // 1024 blocks

    hipLaunchKernelGGL(dilate_attn_kernel, dim3(grid), dim3(block), 0, stream,
                       q, k, v, out);
}

// Round 2
// 200.363 us; speedup vs baseline: 1.0003x; 1.0003x over previous
//
#include <hip/hip_runtime.h>
#include <math.h>

#define NPOS 4096
#define DCH  512
#define HD   32
#define NH   16
#define KW   9
#define DIL  3
#define PAD  12
#define CSPLIT 4              // lanes per token (channel split)
#define CPT  (HD / CSPLIT)    // channels per thread = 8

__global__ __launch_bounds__(256) void dilate_attn_kernel(
    const float* __restrict__ q,
    const float* __restrict__ k,
    const float* __restrict__ v,
    float* __restrict__ out)
{
    const int g  = blockIdx.x * blockDim.x + threadIdx.x;
    const int cs = g & (CSPLIT - 1);          // which channel quarter
    const int n  = (g >> 2) & (NPOS - 1);     // token position
    const int bh = g >> 14;                   // b*16 + h

    const size_t chbase = (size_t)bh * HD * NPOS;
    const int cb = cs * CPT;                  // first channel this lane owns
    const float* qp = q + chbase + (size_t)cb * NPOS + n;
    const float* kp = k + chbase + (size_t)cb * NPOS;
    const float* vp = v + chbase + (size_t)cb * NPOS;

    // Window indices + validity (independent of channel)
    int   idx[KW];
    float validf[KW];
#pragma unroll
    for (int j = 0; j < KW; ++j) {
        int i0 = n + j * DIL - PAD;
        validf[j] = (i0 >= 0 && i0 < NPOS) ? 1.0f : 0.0f;
        idx[j] = min(max(i0, 0), NPOS - 1);
    }

    // Partial scores over this lane's 8 channels
    float s[KW];
#pragma unroll
    for (int j = 0; j < KW; ++j) s[j] = 0.0f;

#pragma unroll
    for (int i = 0; i < CPT; ++i) {
        float qc = qp[(size_t)i * NPOS];
        const float* kc = kp + (size_t)i * NPOS;
#pragma unroll
        for (int j = 0; j < KW; ++j)
            s[j] = fmaf(qc, kc[idx[j]], s[j]);
    }

    // Reduce partial scores across the 4 channel-split lanes (lanes ^1, ^2)
#pragma unroll
    for (int j = 0; j < KW; ++j) {
        s[j] += __shfl_xor(s[j], 1);
        s[j] += __shfl_xor(s[j], 2);
    }

    // Softmax over 9 slots; invalid slots have logit exactly 0 (ref semantics)
    const float scale = 0.17677669529663687f;  // 32^-0.5
    float m = -INFINITY;
#pragma unroll
    for (int j = 0; j < KW; ++j) {
        s[j] = s[j] * scale * validf[j];
        m = fmaxf(m, s[j]);
    }
    float sum = 0.0f;
    float p[KW];
#pragma unroll
    for (int j = 0; j < KW; ++j) {
        float e = __expf(s[j] - m);
        p[j] = e;
        sum += e;
    }
    float inv = 1.0f / sum;
#pragma unroll
    for (int j = 0; j < KW; ++j)
        p[j] *= inv * validf[j];   // invalid taps contribute nothing to output

    // Output for this lane's 8 channels
    float o[CPT];
#pragma unroll
    for (int i = 0; i < CPT; ++i) {
        const float* vc = vp + (size_t)i * NPOS;
        float acc = 0.0f;
#pragma unroll
        for (int j = 0; j < KW; ++j)
            acc = fmaf(p[j], vc[idx[j]], acc);
        o[i] = acc;
    }

    // Store: out[(b*NPOS + n)*DCH + h*HD + cb .. +8] -> 2 float4 (coalesced:
    // consecutive lanes = consecutive cs -> consecutive 8-float chunks)
    const int b  = bh >> 4;
    const int hh = bh & (NH - 1);
    float* op = out + ((size_t)(b * NPOS + n)) * DCH + hh * HD + cb;
    float4* op4 = reinterpret_cast<float4*>(op);
    op4[0] = make_float4(o[0], o[1], o[2], o[3]);
    op4[1] = make_float4(o[4], o[5], o[6], o[7]);
}

extern "C" void kernel_launch(void* const* d_in, const int* in_sizes, int n_in,
                              void* d_out, int out_size, void* d_ws, size_t ws_size,
                              hipStream_t stream) {
    const float* q = (const float*)d_in[0];
    const float* k = (const float*)d_in[1];
    const float* v = (const float*)d_in[2];
    float* out = (float*)d_out;

    const int total = 4 * NH * NPOS * CSPLIT;  // B * heads * L * channel-split
    const int block = 256;
    const int grid  = total / block;           // 4096 blocks

    hipLaunchKernelGGL(dilate_attn_kernel, dim3(grid), dim3(block), 0, stream,
                       q, k, v, out);
}

// Round 3
// 176.896 us; speedup vs baseline: 1.1330x; 1.1327x over previous
//
#include <hip/hip_runtime.h>
#include <math.h>

#define NPOS 4096
#define DCH  512
#define HD   32
#define NH   16
#define KW   9
#define DIL  3
#define PAD  12
#define CSPLIT 4              // lanes per token-group (channel split)
#define CPT  (HD / CSPLIT)    // channels per thread = 8
#define TPT  4                // tokens per thread
#define SPAN 28               // taps for 4 consecutive tokens span 28 tokens
#define NF4  (SPAN / 4)       // 7 float4 per channel span

__global__ __launch_bounds__(256) void dilate_attn_kernel(
    const float* __restrict__ q,
    const float* __restrict__ k,
    const float* __restrict__ v,
    float* __restrict__ out)
{
    const int g  = blockIdx.x * blockDim.x + threadIdx.x;
    const int cs = g & (CSPLIT - 1);              // channel quarter (lane quad)
    const int tg = (g >> 2) & (NPOS / TPT - 1);   // token group (1024 per row)
    const int bh = g >> 12;                       // b*16 + h

    const int n0 = tg * TPT;                      // first token, multiple of 4
    const size_t chbase = (size_t)bh * HD * NPOS + (size_t)cs * CPT * NPOS;
    const float* qp = q + chbase;
    const float* kp = k + chbase;
    const float* vp = v + chbase;

    const bool interior = (n0 >= PAD) && (n0 + TPT - 1 + PAD <= NPOS - 1);

    // ---------- Pass 1: scores s[t][j] over this lane's 8 channels ----------
    float s[TPT][KW];
#pragma unroll
    for (int t = 0; t < TPT; ++t)
#pragma unroll
        for (int j = 0; j < KW; ++j) s[t][j] = 0.0f;

    if (interior) {
        const int ws = n0 - PAD;                  // span start, float4-aligned
        for (int i = 0; i < CPT; ++i) {
            const float* kc = kp + (size_t)i * NPOS;
            const float4* kv4 = reinterpret_cast<const float4*>(kc + ws);
            float w[SPAN];
#pragma unroll
            for (int u = 0; u < NF4; ++u) {
                float4 x = kv4[u];
                w[4*u] = x.x; w[4*u+1] = x.y; w[4*u+2] = x.z; w[4*u+3] = x.w;
            }
            float4 qv = *reinterpret_cast<const float4*>(qp + (size_t)i * NPOS + n0);
            float qt[TPT] = {qv.x, qv.y, qv.z, qv.w};
#pragma unroll
            for (int t = 0; t < TPT; ++t)
#pragma unroll
                for (int j = 0; j < KW; ++j)
                    s[t][j] = fmaf(qt[t], w[t + 3*j], s[t][j]);
        }
    } else {
        for (int i = 0; i < CPT; ++i) {
            const float* kc = kp + (size_t)i * NPOS;
            float4 qv = *reinterpret_cast<const float4*>(qp + (size_t)i * NPOS + n0);
            float qt[TPT] = {qv.x, qv.y, qv.z, qv.w};
#pragma unroll
            for (int t = 0; t < TPT; ++t)
#pragma unroll
                for (int j = 0; j < KW; ++j) {
                    int ii = n0 + t + 3*j - PAD;
                    int ic = min(max(ii, 0), NPOS - 1);
                    s[t][j] = fmaf(qt[t], kc[ic], s[t][j]);
                }
        }
    }

    // ---------- Reduce partial scores across the 4 channel-split lanes ------
#pragma unroll
    for (int t = 0; t < TPT; ++t)
#pragma unroll
        for (int j = 0; j < KW; ++j) {
            float x = s[t][j];
            x += __shfl_xor(x, 1);
            x += __shfl_xor(x, 2);
            s[t][j] = x;
        }

    // ---------- Softmax per token (invalid taps: logit exactly 0) -----------
    const float scale = 0.17677669529663687f;     // 32^-0.5
#pragma unroll
    for (int t = 0; t < TPT; ++t) {
        float m = -INFINITY;
#pragma unroll
        for (int j = 0; j < KW; ++j) {
            float valid = ((unsigned)(n0 + t + 3*j - PAD) < NPOS) ? 1.0f : 0.0f;
            float x = s[t][j] * scale * valid;
            s[t][j] = x;
            m = fmaxf(m, x);
        }
        float sum = 0.0f;
#pragma unroll
        for (int j = 0; j < KW; ++j) {
            float e = __expf(s[t][j] - m);
            s[t][j] = e;
            sum += e;
        }
        float inv = 1.0f / sum;
#pragma unroll
        for (int j = 0; j < KW; ++j) {
            float valid = ((unsigned)(n0 + t + 3*j - PAD) < NPOS) ? 1.0f : 0.0f;
            s[t][j] *= inv * valid;               // s now holds probabilities
        }
    }

    // ---------- Pass 2: output o[t][i] ----------
    float o[TPT][CPT];
#pragma unroll
    for (int t = 0; t < TPT; ++t)
#pragma unroll
        for (int i = 0; i < CPT; ++i) o[t][i] = 0.0f;

    if (interior) {
        const int ws = n0 - PAD;
        for (int i = 0; i < CPT; ++i) {
            const float* vc = vp + (size_t)i * NPOS;
            const float4* vv4 = reinterpret_cast<const float4*>(vc + ws);
            float w[SPAN];
#pragma unroll
            for (int u = 0; u < NF4; ++u) {
                float4 x = vv4[u];
                w[4*u] = x.x; w[4*u+1] = x.y; w[4*u+2] = x.z; w[4*u+3] = x.w;
            }
#pragma unroll
            for (int t = 0; t < TPT; ++t)
#pragma unroll
                for (int j = 0; j < KW; ++j)
                    o[t][i] = fmaf(s[t][j], w[t + 3*j], o[t][i]);
        }
    } else {
        for (int i = 0; i < CPT; ++i) {
            const float* vc = vp + (size_t)i * NPOS;
#pragma unroll
            for (int t = 0; t < TPT; ++t)
#pragma unroll
                for (int j = 0; j < KW; ++j) {
                    int ii = n0 + t + 3*j - PAD;
                    int ic = min(max(ii, 0), NPOS - 1);
                    o[t][i] = fmaf(s[t][j], vc[ic], o[t][i]);  // p already 0 if invalid
                }
        }
    }

    // ---------- Store: 2 float4 per token ----------
    const int b  = bh >> 4;
    const int hh = bh & (NH - 1);
#pragma unroll
    for (int t = 0; t < TPT; ++t) {
        float* op = out + ((size_t)(b * NPOS + n0 + t)) * DCH + hh * HD + cs * CPT;
        float4* op4 = reinterpret_cast<float4*>(op);
        op4[0] = make_float4(o[t][0], o[t][1], o[t][2], o[t][3]);
        op4[1] = make_float4(o[t][4], o[t][5], o[t][6], o[t][7]);
    }
}

extern "C" void kernel_launch(void* const* d_in, const int* in_sizes, int n_in,
                              void* d_out, int out_size, void* d_ws, size_t ws_size,
                              hipStream_t stream) {
    const float* q = (const float*)d_in[0];
    const float* k = (const float*)d_in[1];
    const float* v = (const float*)d_in[2];
    float* out = (float*)d_out;

    const int total = 4 * NH * (NPOS / TPT) * CSPLIT;  // 262144 threads
    const int block = 256;
    const int grid  = total / block;                   // 1024 blocks

    hipLaunchKernelGGL(dilate_attn_kernel, dim3(grid), dim3(block), 0, stream,
                       q, k, v, out);
}

// Round 4
// 147.820 us; speedup vs baseline: 1.3559x; 1.1967x over previous
//
#include <hip/hip_runtime.h>
#include <math.h>

#define NPOS 4096
#define DCH  512
#define HD   32
#define NH   16
#define KW   9
#define DIL  3
#define PAD  12
#define TILE   128
#define NTILES (NPOS / TILE)       // 32
#define SPANT  (TILE + 2*PAD)      // 152 tokens staged per tile
#define ROWF4  (SPANT / 4)         // 38 float4 per channel row
#define SLDS   156                 // LDS row stride in floats (pad vs 152)
#define CSPL   8                   // channel-split lanes per token-group
#define CPT    (HD / CSPL)         // 4 channels per thread
#define TPT    4                   // tokens per thread
#define WSPAN  28                  // 4 tokens x 9 taps span 28 tokens

__global__ __launch_bounds__(256) void dilate_attn_kernel(
    const float* __restrict__ q,
    const float* __restrict__ k,
    const float* __restrict__ v,
    float* __restrict__ out)
{
    __shared__ float ks[HD * SLDS];
    __shared__ float vs[HD * SLDS];

    const int bh   = blockIdx.x >> 5;            // 0..63  (b*16+h)
    const int tile = blockIdx.x & (NTILES - 1);  // 0..31
    const int n0t  = tile * TILE;                // first token of tile
    const int ws   = n0t - PAD;                  // staged span start (may be <0)

    const size_t cb = (size_t)bh * HD * NPOS;
    const float* kg = k + cb;
    const float* vg = v + cb;
    const float* qg = q + cb;

    // ---------------- Stage k,v spans into LDS (coalesced float4) ----------
    const bool easy = (ws >= 0) && (ws + SPANT <= NPOS);
    for (int p = threadIdx.x; p < HD * ROWF4; p += 256) {
        int row = p / ROWF4;                     // channel 0..31
        int c4  = p - row * ROWF4;               // float4 col 0..37
        int g0  = ws + c4 * 4;
        const float* kr = kg + (size_t)row * NPOS;
        const float* vr = vg + (size_t)row * NPOS;
        float4 kk, vv;
        if (easy || (g0 >= 0 && g0 + 4 <= NPOS)) {
            kk = *(const float4*)(kr + g0);
            vv = *(const float4*)(vr + g0);
        } else {                                  // edge tiles: clamped scalar
            int i0 = min(max(g0 + 0, 0), NPOS - 1);
            int i1 = min(max(g0 + 1, 0), NPOS - 1);
            int i2 = min(max(g0 + 2, 0), NPOS - 1);
            int i3 = min(max(g0 + 3, 0), NPOS - 1);
            kk = make_float4(kr[i0], kr[i1], kr[i2], kr[i3]);
            vv = make_float4(vr[i0], vr[i1], vr[i2], vr[i3]);
        }
        *(float4*)&ks[row * SLDS + c4 * 4] = kk;
        *(float4*)&vs[row * SLDS + c4 * 4] = vv;
    }

    // ---------------- q loads (global, coalesced; overlap staging) ---------
    const int cs = threadIdx.x & (CSPL - 1);     // lane&7: channel octet slot
    const int lg = threadIdx.x >> 3;             // 0..31: token group in tile
    const int n0 = n0t + lg * TPT;               // first token this thread owns

    float4 qv[CPT];
#pragma unroll
    for (int i = 0; i < CPT; ++i) {
        int ch = cs * CPT + i;
        qv[i] = *(const float4*)(qg + (size_t)ch * NPOS + n0);
    }

    __syncthreads();

    // ---------------- Pass 1: partial scores from LDS k ---------------------
    float s[TPT][KW];
#pragma unroll
    for (int t = 0; t < TPT; ++t)
#pragma unroll
        for (int j = 0; j < KW; ++j) s[t][j] = 0.0f;

#pragma unroll
    for (int i = 0; i < CPT; ++i) {
        int row = cs * CPT + i;
        const float4* wp = (const float4*)&ks[row * SLDS + lg * TPT];
        float w[WSPAN];
#pragma unroll
        for (int u = 0; u < WSPAN / 4; ++u) {
            float4 x = wp[u];
            w[4*u] = x.x; w[4*u+1] = x.y; w[4*u+2] = x.z; w[4*u+3] = x.w;
        }
        float qt[TPT] = {qv[i].x, qv[i].y, qv[i].z, qv[i].w};
#pragma unroll
        for (int t = 0; t < TPT; ++t)
#pragma unroll
            for (int j = 0; j < KW; ++j)
                s[t][j] = fmaf(qt[t], w[t + 3*j], s[t][j]);
    }

    // Reduce partial scores across the 8 channel-split lanes
#pragma unroll
    for (int t = 0; t < TPT; ++t)
#pragma unroll
        for (int j = 0; j < KW; ++j) {
            float x = s[t][j];
            x += __shfl_xor(x, 1);
            x += __shfl_xor(x, 2);
            x += __shfl_xor(x, 4);
            s[t][j] = x;
        }

    // ---------------- Softmax per token (invalid taps: logit exactly 0) ----
    const float scale = 0.17677669529663687f;    // 32^-0.5
#pragma unroll
    for (int t = 0; t < TPT; ++t) {
        float m = -INFINITY;
#pragma unroll
        for (int j = 0; j < KW; ++j) {
            float valid = ((unsigned)(n0 + t + 3*j - PAD) < NPOS) ? 1.0f : 0.0f;
            float x = s[t][j] * scale * valid;
            s[t][j] = x;
            m = fmaxf(m, x);
        }
        float sum = 0.0f;
#pragma unroll
        for (int j = 0; j < KW; ++j) {
            float e = __expf(s[t][j] - m);
            s[t][j] = e;
            sum += e;
        }
        float inv = 1.0f / sum;
#pragma unroll
        for (int j = 0; j < KW; ++j) {
            float valid = ((unsigned)(n0 + t + 3*j - PAD) < NPOS) ? 1.0f : 0.0f;
            s[t][j] *= inv * valid;              // s now holds probabilities
        }
    }

    // ---------------- Pass 2: output from LDS v ------------------------------
    float o[TPT][CPT];
#pragma unroll
    for (int t = 0; t < TPT; ++t)
#pragma unroll
        for (int i = 0; i < CPT; ++i) o[t][i] = 0.0f;

#pragma unroll
    for (int i = 0; i < CPT; ++i) {
        int row = cs * CPT + i;
        const float4* wp = (const float4*)&vs[row * SLDS + lg * TPT];
        float w[WSPAN];
#pragma unroll
        for (int u = 0; u < WSPAN / 4; ++u) {
            float4 x = wp[u];
            w[4*u] = x.x; w[4*u+1] = x.y; w[4*u+2] = x.z; w[4*u+3] = x.w;
        }
#pragma unroll
        for (int t = 0; t < TPT; ++t)
#pragma unroll
            for (int j = 0; j < KW; ++j)
                o[t][i] = fmaf(s[t][j], w[t + 3*j], o[t][i]);
    }

    // ---------------- Store: one float4 per token (octet -> 128B/token) ----
    const int b  = bh >> 4;
    const int hh = bh & (NH - 1);
#pragma unroll
    for (int t = 0; t < TPT; ++t) {
        float* op = out + ((size_t)(b * NPOS + n0 + t)) * DCH + hh * HD + cs * CPT;
        *(float4*)op = make_float4(o[t][0], o[t][1], o[t][2], o[t][3]);
    }
}

extern "C" void kernel_launch(void* const* d_in, const int* in_sizes, int n_in,
                              void* d_out, int out_size, void* d_ws, size_t ws_size,
                              hipStream_t stream) {
    const float* q = (const float*)d_in[0];
    const float* k = (const float*)d_in[1];
    const float* v = (const float*)d_in[2];
    float* out = (float*)d_out;

    const int grid = 4 * NH * NTILES;   // 64 bh * 32 tiles = 2048 blocks
    hipLaunchKernelGGL(dilate_attn_kernel, dim3(grid), dim3(256), 0, stream,
                       q, k, v, out);
}